// Round 1
// baseline (181.404 us; speedup 1.0000x reference)
//
#include <hip/hip_runtime.h>
#include <hip/hip_bf16.h>

#define NUM_USER 100000
#define K_NEIGH 32
#define DIM 64

__global__ __launch_bounds__(256) void user_graph_gather_kernel(
    const float* __restrict__ features,
    const int*   __restrict__ graph,
    const float* __restrict__ matrix,
    float*       __restrict__ out) {
  int t = blockIdx.x * blockDim.x + threadIdx.x;
  int u = t >> 6;          // user index
  int d = t & 63;          // dim index
  if (u >= NUM_USER) return;

  const int*   g = graph  + (size_t)u * K_NEIGH;
  const float* w = matrix + (size_t)u * K_NEIGH;

  float acc = 0.f;
#pragma unroll
  for (int k = 0; k < K_NEIGH; ++k) {
    int   idx = g[k];          // wave-uniform -> broadcast from cache
    float wk  = w[k];          // wave-uniform
    acc += wk * features[(size_t)idx * DIM + d];  // coalesced 256B row read
  }
  out[(size_t)u * DIM + d] = acc;
}

extern "C" void kernel_launch(void* const* d_in, const int* in_sizes, int n_in,
                              void* d_out, int out_size, void* d_ws, size_t ws_size,
                              hipStream_t stream) {
  const float* features = (const float*)d_in[0];
  const int*   graph    = (const int*)d_in[1];
  const float* matrix   = (const float*)d_in[2];
  float*       out      = (float*)d_out;

  const int total = NUM_USER * DIM;           // 6,400,000 threads
  const int block = 256;
  const int grid  = (total + block - 1) / block;  // 25000 blocks
  user_graph_gather_kernel<<<grid, block, 0, stream>>>(features, graph, matrix, out);
}